// Round 7
// baseline (169.974 us; speedup 1.0000x reference)
//
#include <hip/hip_runtime.h>
#include <hip/hip_bf16.h>

#define NCLASS 19
#define BINS 512
#define NB (NCLASS * BINS)  // 9728 bins
#define NREP 4
#define RPAD 8              // words; shifts each replica's bank phase by 8
#define RSTRIDE (NB + RPAD)
#define IGNORE_IDX (-100)
#define HW_SHIFT 18  // 512*512 = 2^18 (fixed problem shape)
#define HW_C (1 << HW_SHIFT)

// Load one 2-pixel set: 19 float2 logit streams + int2 labels.
#define LOADSET(V, LB, PIX)                                                  \
  {                                                                          \
    int n_ = (PIX) >> HW_SHIFT;                                              \
    int hw_ = (PIX) & (HW_C - 1);                                            \
    const float* lp_ =                                                       \
        logits + (((size_t)n_ * NCLASS) << HW_SHIFT) + hw_;                  \
    _Pragma("unroll") for (int c_ = 0; c_ < NCLASS; ++c_) {                  \
      float2 q_ = *(const float2*)(lp_ + ((size_t)c_ << HW_SHIFT));          \
      V[c_][0] = q_.x;                                                       \
      V[c_][1] = q_.y;                                                       \
    }                                                                        \
    LB = *(const int2*)(labels + (PIX));                                     \
  }

// Softmax + 2x19 histogram atomics for one 2-pixel set.
#define PROCSET(V, LB)                                                       \
  {                                                                          \
    float m0_ = -3.4e38f, m1_ = -3.4e38f;                                    \
    _Pragma("unroll") for (int c_ = 0; c_ < NCLASS; ++c_) {                  \
      m0_ = fmaxf(m0_, V[c_][0]);                                            \
      m1_ = fmaxf(m1_, V[c_][1]);                                            \
    }                                                                        \
    float s0_ = 0.f, s1_ = 0.f;                                              \
    _Pragma("unroll") for (int c_ = 0; c_ < NCLASS; ++c_) {                  \
      V[c_][0] = __expf(V[c_][0] - m0_); s0_ += V[c_][0];                    \
      V[c_][1] = __expf(V[c_][1] - m1_); s1_ += V[c_][1];                    \
    }                                                                        \
    float i0_ = 1.0f / s0_, i1_ = 1.0f / s1_;                                \
    int l0_ = LB.x, l1_ = LB.y;                                              \
    _Pragma("unroll") for (int c_ = 0; c_ < NCLASS; ++c_) {                  \
      if (l0_ != IGNORE_IDX) {                                               \
        float pr_ = V[c_][0] * i0_;                                          \
        bool pos_ = (c_ == l0_);                                             \
        float e_ = pos_ ? (1.0f - pr_) : pr_;                                \
        int b_ = min(BINS - 1, (int)(e_ * (float)BINS));                     \
        atomicAdd(&sh[rep + (c_ << 9) + b_], pos_ ? 0x10000u : 1u);          \
      }                                                                      \
      if (l1_ != IGNORE_IDX) {                                               \
        float pr_ = V[c_][1] * i1_;                                          \
        bool pos_ = (c_ == l1_);                                             \
        float e_ = pos_ ? (1.0f - pr_) : pr_;                                \
        int b_ = min(BINS - 1, (int)(e_ * (float)BINS));                     \
        atomicAdd(&sh[rep + (c_ << 9) + b_], pos_ ? 0x10000u : 1u);          \
      }                                                                      \
    }                                                                        \
  }

// ---------------------------------------------------------------------------
// Phase 1: R5's proven core (2 px/thread float2, 4-way lane-replicated LDS
// histogram, u32-packed pos<<16|neg) + register double-buffer prefetch: set
// k+1's loads are issued before set k's compute, so the 20 global loads stay
// outstanding under ~500 cyc of compute+DS. Named A/B sets keep all register
// indexing compile-time (rule #20). __launch_bounds__(1024,4) caps VGPR at
// 128 -> 16 waves/CU preserved. ppb <= 65535 keeps u16 fields safe.
// ---------------------------------------------------------------------------
__global__ void __launch_bounds__(1024, 4) hist_pf(
    const float* __restrict__ logits, const int* __restrict__ labels,
    unsigned* __restrict__ copies, int P, int ppb) {
  extern __shared__ unsigned sh[];  // NREP*RSTRIDE words ~= 152 KB
  for (int i = threadIdx.x; i < NREP * RSTRIDE; i += 1024) sh[i] = 0u;
  __syncthreads();

  const int rep = (threadIdx.x & 3) * RSTRIDE;
  const int STEP = 1024 * 2;
  int p1 = min(P, blockIdx.x * ppb + ppb);
  int p = blockIdx.x * ppb + (int)threadIdx.x * 2;

  float va[NCLASS][2], vb[NCLASS][2];
  int2 la, lb;
  bool has = p < p1;
  if (has) LOADSET(va, la, p);
  while (has) {
    int pn = p + STEP;
    bool hasn = pn < p1;
    if (hasn) LOADSET(vb, lb, pn);  // prefetch next set
    PROCSET(va, la);
    p = pn;
    has = hasn;
    if (!has) break;
    pn = p + STEP;
    hasn = pn < p1;
    if (hasn) LOADSET(va, la, pn);  // prefetch next set
    PROCSET(vb, lb);
    p = pn;
    has = hasn;
  }
  __syncthreads();

  unsigned* dst = copies + (size_t)blockIdx.x * NB;
  for (int i = threadIdx.x; i < NB; i += 1024)
    dst[i] =
        sh[i] + sh[RSTRIDE + i] + sh[2 * RSTRIDE + i] + sh[3 * RSTRIDE + i];
}

// ---------------------------------------------------------------------------
// Phase 2 (fused tail): per class, fold the R copies directly (coalesced
// 256B segments per r), then suffix scan over bins and Lovasz J accumulation.
// loss_c = (1/BINS) * sum_{b>=1} J_b with (CP,CN) inclusive suffix counts.
// ---------------------------------------------------------------------------
__global__ void __launch_bounds__(256) scan_direct(
    const unsigned* __restrict__ copies, float* __restrict__ partial, int R) {
  int c = blockIdx.x;
  __shared__ unsigned long long bins[BINS];
  __shared__ unsigned long long arr[256];
  __shared__ unsigned long long wsum[4];
  __shared__ float fsum[4];
  int tid = threadIdx.x;

  for (int i = tid; i < BINS; i += 256) {
    unsigned long long a = 0;
    for (int r = 0; r < R; ++r) {
      unsigned v = copies[(size_t)r * NB + (c << 9) + i];
      a += ((unsigned long long)(v >> 16) << 32) |
           (unsigned long long)(v & 0xffffu);
    }
    bins[i] = a;
  }
  __syncthreads();

  // class total (for nPos)
  unsigned long long t = 0;
  for (int i = tid; i < BINS; i += 256) t += bins[i];
  for (int off = 32; off > 0; off >>= 1) t += __shfl_down(t, off, 64);
  int lane = tid & 63, w = tid >> 6;
  if (lane == 0) wsum[w] = t;
  __syncthreads();
  unsigned long long total = wsum[0] + wsum[1] + wsum[2] + wsum[3];
  float nPos = (float)(unsigned)(total >> 32);

  // suffix scan, 256-bin rows from the top, carry in `above`
  unsigned long long above = 0;
  float acc = 0.f;
  for (int r = BINS / 256 - 1; r >= 0; --r) {
    arr[tid] = bins[r * 256 + tid];
    __syncthreads();
    for (int off = 1; off < 256; off <<= 1) {
      unsigned long long add = (tid + off < 256) ? arr[tid + off] : 0ull;
      __syncthreads();
      arr[tid] += add;
      __syncthreads();
    }
    unsigned long long suff = arr[tid] + above;
    unsigned long long rowTot = arr[0];
    __syncthreads();

    int gb = r * 256 + tid;
    if (gb >= 1) {
      float CP = (float)(unsigned)(suff >> 32);
      float CN = (float)(unsigned)(suff & 0xffffffffull);
      float uni = nPos + CN;
      if (uni > 0.f) acc += 1.0f - (nPos - CP) / uni;
    }
    above += rowTot;
  }

  for (int off = 32; off > 0; off >>= 1) acc += __shfl_down(acc, off, 64);
  if (lane == 0) fsum[w] = acc;
  __syncthreads();
  if (tid == 0) partial[c] = fsum[0] + fsum[1] + fsum[2] + fsum[3];
}

// ---------------------------------------------------------------------------
// Phase 3: mean over classes (fixed-order, deterministic).
// ---------------------------------------------------------------------------
__global__ void __launch_bounds__(64) lovasz_final(
    const float* __restrict__ partial, float* __restrict__ out, int n,
    float scale) {
  float acc = 0.f;
  for (int i = threadIdx.x; i < n; i += 64) acc += partial[i];
  for (int off = 32; off > 0; off >>= 1) acc += __shfl_down(acc, off, 64);
  if (threadIdx.x == 0) out[0] = acc * scale;
}

extern "C" void kernel_launch(void* const* d_in, const int* in_sizes, int n_in,
                              void* d_out, int out_size, void* d_ws,
                              size_t ws_size, hipStream_t stream) {
  const float* logits = (const float*)d_in[0];
  const int* labels = (const int*)d_in[1];
  float* out = (float*)d_out;

  const int P = in_sizes[1];  // 8*512*512 = 2,097,152

  // R = copy count = grid size; 256 = 1 block/CU. Shrink if ws is tiny.
  int R = 256;
  while (R > 32 && (size_t)R * NB * 4 + 4096 > ws_size) R >>= 1;
  // ppb multiple of 2048 keeps float2/int2 loads aligned. 8192 at R=256.
  int ppb = ((P + R - 1) / R + 2047) & ~2047;

  char* ws = (char*)d_ws;
  unsigned* copies = (unsigned*)ws;
  float* partial = (float*)(ws + (size_t)R * NB * 4);

  size_t ldsBytes = (size_t)NREP * RSTRIDE * 4;  // ~152 KB -> 1 block/CU

  hist_pf<<<R, 1024, ldsBytes, stream>>>(logits, labels, copies, P, ppb);
  scan_direct<<<NCLASS, 256, 0, stream>>>(copies, partial, R);
  lovasz_final<<<1, 64, 0, stream>>>(partial, out, NCLASS,
                                     1.0f / ((float)BINS * (float)NCLASS));
}

// Round 8
// 52.970 us; speedup vs baseline: 3.2089x; 3.2089x over previous
//
#include <hip/hip_runtime.h>
#include <hip/hip_bf16.h>

#define NCLASS 19
#define BINS 512
#define NB (NCLASS * BINS)  // 9728 bins
#define NREP 4
#define RPAD 8              // words; shifts each replica's bank phase by 8
#define RSTRIDE (NB + RPAD)
#define SLICES 8
#define IGNORE_IDX (-100)
#define HW_SHIFT 18  // 512*512 = 2^18 (fixed problem shape)
#define HW_C (1 << HW_SHIFT)

// Load one 2-pixel set: 19 float2 logit streams + int2 labels.
#define LOADSET(V, LB, PIX)                                                  \
  {                                                                          \
    int n_ = (PIX) >> HW_SHIFT;                                              \
    int hw_ = (PIX) & (HW_C - 1);                                            \
    const float* lp_ =                                                       \
        logits + (((size_t)n_ * NCLASS) << HW_SHIFT) + hw_;                  \
    _Pragma("unroll") for (int c_ = 0; c_ < NCLASS; ++c_) {                  \
      float2 q_ = *(const float2*)(lp_ + ((size_t)c_ << HW_SHIFT));          \
      V[c_][0] = q_.x;                                                       \
      V[c_][1] = q_.y;                                                       \
    }                                                                        \
    LB = *(const int2*)(labels + (PIX));                                     \
  }

// Softmax + 2x19 histogram atomics for one 2-pixel set.
#define PROCSET(V, LB)                                                       \
  {                                                                          \
    float m0_ = -3.4e38f, m1_ = -3.4e38f;                                    \
    _Pragma("unroll") for (int c_ = 0; c_ < NCLASS; ++c_) {                  \
      m0_ = fmaxf(m0_, V[c_][0]);                                            \
      m1_ = fmaxf(m1_, V[c_][1]);                                            \
    }                                                                        \
    float s0_ = 0.f, s1_ = 0.f;                                              \
    _Pragma("unroll") for (int c_ = 0; c_ < NCLASS; ++c_) {                  \
      V[c_][0] = __expf(V[c_][0] - m0_); s0_ += V[c_][0];                    \
      V[c_][1] = __expf(V[c_][1] - m1_); s1_ += V[c_][1];                    \
    }                                                                        \
    float i0_ = 1.0f / s0_, i1_ = 1.0f / s1_;                                \
    int l0_ = LB.x, l1_ = LB.y;                                              \
    _Pragma("unroll") for (int c_ = 0; c_ < NCLASS; ++c_) {                  \
      if (l0_ != IGNORE_IDX) {                                               \
        float pr_ = V[c_][0] * i0_;                                          \
        bool pos_ = (c_ == l0_);                                             \
        float e_ = pos_ ? (1.0f - pr_) : pr_;                                \
        int b_ = min(BINS - 1, (int)(e_ * (float)BINS));                     \
        atomicAdd(&sh[rep + (c_ << 9) + b_], pos_ ? 0x10000u : 1u);          \
      }                                                                      \
      if (l1_ != IGNORE_IDX) {                                               \
        float pr_ = V[c_][1] * i1_;                                          \
        bool pos_ = (c_ == l1_);                                             \
        float e_ = pos_ ? (1.0f - pr_) : pr_;                                \
        int b_ = min(BINS - 1, (int)(e_ * (float)BINS));                     \
        atomicAdd(&sh[rep + (c_ << 9) + b_], pos_ ? 0x10000u : 1u);          \
      }                                                                      \
    }                                                                        \
  }

// ---------------------------------------------------------------------------
// Phase 1 (proven, ~31 us ~= 90% of its HBM floor): 2 px/thread float2 loads,
// 4-way lane-replicated LDS histogram (u32-packed pos<<16|neg), register
// double-buffer prefetch (set k+1's 20 loads issued before set k's compute).
// Named A/B register sets keep indexing compile-time (rule #20).
// __launch_bounds__(1024,4) caps VGPR at 128 -> 16 waves/CU.
// ---------------------------------------------------------------------------
__global__ void __launch_bounds__(1024, 4) hist_pf(
    const float* __restrict__ logits, const int* __restrict__ labels,
    unsigned* __restrict__ copies, int P, int ppb) {
  extern __shared__ unsigned sh[];  // NREP*RSTRIDE words ~= 152 KB
  for (int i = threadIdx.x; i < NREP * RSTRIDE; i += 1024) sh[i] = 0u;
  __syncthreads();

  const int rep = (threadIdx.x & 3) * RSTRIDE;
  const int STEP = 1024 * 2;
  int p1 = min(P, blockIdx.x * ppb + ppb);
  int p = blockIdx.x * ppb + (int)threadIdx.x * 2;

  float va[NCLASS][2], vb[NCLASS][2];
  int2 la, lb;
  bool has = p < p1;
  if (has) LOADSET(va, la, p);
  while (has) {
    int pn = p + STEP;
    bool hasn = pn < p1;
    if (hasn) LOADSET(vb, lb, pn);  // prefetch next set
    PROCSET(va, la);
    p = pn;
    has = hasn;
    if (!has) break;
    pn = p + STEP;
    hasn = pn < p1;
    if (hasn) LOADSET(va, la, pn);  // prefetch next set
    PROCSET(vb, lb);
    p = pn;
    has = hasn;
  }
  __syncthreads();

  unsigned* dst = copies + (size_t)blockIdx.x * NB;
  for (int i = threadIdx.x; i < NB; i += 1024)
    dst[i] =
        sh[i] + sh[RSTRIDE + i] + sh[2 * RSTRIDE + i] + sh[3 * RSTRIDE + i];
}

// ---------------------------------------------------------------------------
// Phase 2: parallel tree-reduce of the R copies (304 blocks). Slice s sums
// copies r==s (mod SLICES) into u64 packed (pos<<32 | neg). Coalesced.
// ---------------------------------------------------------------------------
__global__ void __launch_bounds__(256) reduce_part(
    const unsigned* __restrict__ copies, unsigned long long* __restrict__ part,
    int R) {
  const int nblk = NB / 256;  // 38
  int s = blockIdx.x / nblk;
  int blk = blockIdx.x - s * nblk;
  int cb = blk * 256 + threadIdx.x;
  unsigned long long acc = 0;
  for (int r = s; r < R; r += SLICES) {
    unsigned v = copies[(size_t)r * NB + cb];
    acc += ((unsigned long long)(v >> 16) << 32) |
           (unsigned long long)(v & 0xffffu);
  }
  part[(size_t)s * NB + cb] = acc;
}

// ---------------------------------------------------------------------------
// Phase 3: fold the SLICES partials per class, then suffix scan over bins and
// Lovasz J accumulation. loss_c = (1/BINS) * sum_{b>=1} J_b, with (CP,CN)
// the inclusive suffix counts at bin b.
// ---------------------------------------------------------------------------
__global__ void __launch_bounds__(256) scan19_fold(
    const unsigned long long* __restrict__ part, float* __restrict__ partial) {
  int c = blockIdx.x;
  __shared__ unsigned long long bins[BINS];
  __shared__ unsigned long long arr[256];
  __shared__ unsigned long long wsum[4];
  __shared__ float fsum[4];
  int tid = threadIdx.x;

  for (int i = tid; i < BINS; i += 256) {
    unsigned long long a = 0;
#pragma unroll
    for (int s = 0; s < SLICES; ++s) a += part[(size_t)s * NB + c * BINS + i];
    bins[i] = a;
  }
  __syncthreads();

  // class total (for nPos)
  unsigned long long t = 0;
  for (int i = tid; i < BINS; i += 256) t += bins[i];
  for (int off = 32; off > 0; off >>= 1) t += __shfl_down(t, off, 64);
  int lane = tid & 63, w = tid >> 6;
  if (lane == 0) wsum[w] = t;
  __syncthreads();
  unsigned long long total = wsum[0] + wsum[1] + wsum[2] + wsum[3];
  float nPos = (float)(unsigned)(total >> 32);

  // suffix scan, 256-bin rows from the top, carry in `above`
  unsigned long long above = 0;
  float acc = 0.f;
  for (int r = BINS / 256 - 1; r >= 0; --r) {
    arr[tid] = bins[r * 256 + tid];
    __syncthreads();
    for (int off = 1; off < 256; off <<= 1) {
      unsigned long long add = (tid + off < 256) ? arr[tid + off] : 0ull;
      __syncthreads();
      arr[tid] += add;
      __syncthreads();
    }
    unsigned long long suff = arr[tid] + above;
    unsigned long long rowTot = arr[0];
    __syncthreads();

    int gb = r * 256 + tid;
    if (gb >= 1) {
      float CP = (float)(unsigned)(suff >> 32);
      float CN = (float)(unsigned)(suff & 0xffffffffull);
      float uni = nPos + CN;
      if (uni > 0.f) acc += 1.0f - (nPos - CP) / uni;
    }
    above += rowTot;
  }

  for (int off = 32; off > 0; off >>= 1) acc += __shfl_down(acc, off, 64);
  if (lane == 0) fsum[w] = acc;
  __syncthreads();
  if (tid == 0) partial[c] = fsum[0] + fsum[1] + fsum[2] + fsum[3];
}

// ---------------------------------------------------------------------------
// Phase 4: mean over classes (fixed-order, deterministic).
// ---------------------------------------------------------------------------
__global__ void __launch_bounds__(64) lovasz_final(
    const float* __restrict__ partial, float* __restrict__ out, int n,
    float scale) {
  float acc = 0.f;
  for (int i = threadIdx.x; i < n; i += 64) acc += partial[i];
  for (int off = 32; off > 0; off >>= 1) acc += __shfl_down(acc, off, 64);
  if (threadIdx.x == 0) out[0] = acc * scale;
}

extern "C" void kernel_launch(void* const* d_in, const int* in_sizes, int n_in,
                              void* d_out, int out_size, void* d_ws,
                              size_t ws_size, hipStream_t stream) {
  const float* logits = (const float*)d_in[0];
  const int* labels = (const int*)d_in[1];
  float* out = (float*)d_out;

  const int P = in_sizes[1];  // 8*512*512 = 2,097,152

  // R = copy count = grid size; 256 = 1 block/CU. Shrink if ws is tiny.
  int R = 256;
  while (R > 32 &&
         (size_t)R * NB * 4 + (size_t)SLICES * NB * 8 + 4096 > ws_size)
    R >>= 1;
  // ppb multiple of 2048 keeps float2/int2 loads aligned. 8192 at R=256.
  int ppb = ((P + R - 1) / R + 2047) & ~2047;

  char* ws = (char*)d_ws;
  unsigned* copies = (unsigned*)ws;
  unsigned long long* part = (unsigned long long*)(ws + (size_t)R * NB * 4);
  float* partial = (float*)(part + (size_t)SLICES * NB);

  size_t ldsBytes = (size_t)NREP * RSTRIDE * 4;  // ~152 KB -> 1 block/CU

  hist_pf<<<R, 1024, ldsBytes, stream>>>(logits, labels, copies, P, ppb);
  reduce_part<<<SLICES * (NB / 256), 256, 0, stream>>>(copies, part, R);
  scan19_fold<<<NCLASS, 256, 0, stream>>>(part, partial);
  lovasz_final<<<1, 64, 0, stream>>>(partial, out, NCLASS,
                                     1.0f / ((float)BINS * (float)NCLASS));
}